// Round 11
// baseline (911.062 us; speedup 1.0000x reference)
//
#include <hip/hip_runtime.h>
#include <hip/hip_cooperative_groups.h>

namespace cg = cooperative_groups;

// ---------------------------------------------------------------------------
// GAT 2-layer forward (N=50k, F=128, L1: H=4 x 64, L2: 1 x 64), MI355X.
// Round 11: ONE cooperative mega-kernel (was 8 serial dispatches with ~130us
// of launch/drain overhead). Phases separated by grid.sync():
//  A1 prep+zero | A2 edges+deg | B CSR scan (decoupled lookback, one phase)
//  | C fill srcS | D MFMA gemm | E node1 (gather + MFMA epilogue) | F node2.
// ---------------------------------------------------------------------------

static inline int cdiv(int a, int b) { return (a + b - 1) / b; }
__device__ static inline int cdiv_d(int a, int b) { return (a + b - 1) / b; }

typedef __attribute__((ext_vector_type(8))) short short8;
typedef __attribute__((ext_vector_type(4))) float floatx4;

__device__ __forceinline__ float bf2f(unsigned short u) {
  return __uint_as_float(((unsigned int)u) << 16);
}
__device__ __forceinline__ unsigned short f2bf(float f) {  // RNE
  unsigned int u = __float_as_uint(f);
  unsigned int r = (u + 0x7FFFu + ((u >> 16) & 1u)) >> 16;
  return (unsigned short)r;
}
__device__ __forceinline__ float ldv(const void* p, int i, int bf) {
  return bf ? bf2f(((const unsigned short*)p)[i]) : ((const float*)p)[i];
}
#define NEG_INF (-__builtin_inff())

struct WS {
  size_t srcI, dstI, degcur, rowst, W1c, W1ext, W2sT, v2s, v2d, b1f, b2f,
         srcS, xs1, xs2, A2, need;
};

__host__ __device__ static inline WS ws_layout(int N, int E) {
  const int EP = E + N;
  WS L; size_t o = 0;
#define ALLOC(field, bytes) L.field = o; o = (o + (size_t)(bytes) + 255) & ~(size_t)255;
  ALLOC(srcI, (size_t)EP * 4)
  ALLOC(dstI, (size_t)EP * 4)            // overlaid by A1 (N*8*4 <= EP*4)
  ALLOC(degcur, ((size_t)2 * N + 256) * 4)  // deg | cursor | scanflag
  ALLOC(rowst, (size_t)N * 4)
  ALLOC(W1c, 32768 * 2)
  ALLOC(W1ext, 2048 * 2)
  ALLOC(W2sT, 16384 * 2)
  ALLOC(v2s, 256 * 4)
  ALLOC(v2d, 256 * 4)
  ALLOC(b1f, 256 * 4)
  ALLOC(b2f, 64 * 4)
  ALLOC(srcS, (size_t)EP * 4)
  ALLOC(xs1, (size_t)N * 256 * 2)
  ALLOC(xs2, (size_t)N * 64 * 2)
  ALLOC(A2, (size_t)N * 2 * 4)
#undef ALLOC
  L.need = o;
  return L;
}

__global__ void fill_out_kernel(float* __restrict__ out, int n, float val) {
  int t = blockIdx.x * blockDim.x + threadIdx.x;
  if (t < n) out[t] = val;
}

struct NodeShm {
  unsigned short hb[4][272];   // bf16 h rows, 272-pitch (bank-spread)
  int s_sh[4][64];
  float al_sh[4][64][4];
};

__global__ __launch_bounds__(256, 4) void mega(
    const void* __restrict__ X, const void* __restrict__ EI,
    const void* __restrict__ W1s_, const void* __restrict__ W1d_,
    const void* __restrict__ a1s_, const void* __restrict__ a1d_,
    const void* __restrict__ W2s_, const void* __restrict__ W2d_,
    const void* __restrict__ a2s_, const void* __restrict__ a2d_,
    const void* __restrict__ b1_, const void* __restrict__ b2_,
    char* __restrict__ ws, float* __restrict__ out, int N, int E) {
  cg::grid_group gridg = cg::this_grid();
  __shared__ __align__(16) unsigned short smem[9 * 16 * 136];  // 39168 B
  const int t = threadIdx.x;
  const int EP = E + N;
  const WS L = ws_layout(N, E);
  int* srcI   = (int*)(ws + L.srcI);
  int* dstI   = (int*)(ws + L.dstI);
  int* deg    = (int*)(ws + L.degcur);
  int* cursor = deg + N;
  int* scanflag = deg + 2 * N;
  int* rowst  = (int*)(ws + L.rowst);
  unsigned short* W1c   = (unsigned short*)(ws + L.W1c);
  unsigned short* W1ext = (unsigned short*)(ws + L.W1ext);
  unsigned short* W2sT  = (unsigned short*)(ws + L.W2sT);
  float* v2s = (float*)(ws + L.v2s);
  float* v2d = (float*)(ws + L.v2d);
  float* b1f = (float*)(ws + L.b1f);
  float* b2f = (float*)(ws + L.b2f);
  int* srcS  = (int*)(ws + L.srcS);
  unsigned short* xs1 = (unsigned short*)(ws + L.xs1);
  unsigned short* xs2 = (unsigned short*)(ws + L.xs2);
  float* A2b = (float*)(ws + L.A2);
  float* A1  = (float*)dstI;     // overlay: dstI dead after phase C

  // ---- block-local dtype probes (deterministic; all blocks agree) ----
  __shared__ int pcc, pce;
  if (t == 0) { pcc = 0; pce = 0; }
  __syncthreads();
  {
    const unsigned short* xu = (const unsigned short*)X;
    const unsigned int* eu = (const unsigned int*)EI;
    int l0 = 0, l1 = 0;
    for (int i = t; i < 1024; i += 256) {
      int e0 = (xu[2 * i] >> 7) & 0xFF;
      if (e0 >= 100 && e0 <= 141) l0++;
      if (eu[2 * i + 1] == 0u) l1++;
    }
    atomicAdd(&pcc, l0); atomicAdd(&pce, l1);
  }
  __syncthreads();
  const int bf = (pcc > 512) ? 1 : 0;
  const int e64 = (pce > 512) ? 1 : 0;

  // ======== PHASE A1: zero + weight prep ========
  const int zc = cdiv_d(2 * N + 256, 256);
  const int totalA = zc + 128 + 64 + 3;
  for (int c = blockIdx.x; c < totalA; c += gridDim.x) {
    if (c < zc) {
      int i = c * 256 + t;
      if (i < 2 * N + 256) deg[i] = 0;
    } else if (c < zc + 128) {
      int i = (c - zc) * 256 + t;
      W1c[i] = f2bf(ldv(W1s_, i, bf));
    } else if (c < zc + 192) {
      int i = (c - zc - 128) * 256 + t;
      int k = i >> 6, col = i & 63;
      W2sT[col * 256 + k] = f2bf(ldv(W2s_, i, bf));
    } else if (c == zc + 192) {
      for (int r = 0; r < 4; ++r) {
        int idx = r * 256 + t;
        int k = idx >> 3, q = idx & 7, h = q & 3;
        const void* W = (q < 4) ? W1s_ : W1d_;
        const void* A = (q < 4) ? a1s_ : a1d_;
        float s = 0.f;
        for (int c2 = 0; c2 < 64; ++c2)
          s += ldv(W, k * 256 + h * 64 + c2, bf) * ldv(A, h * 64 + c2, bf);
        W1ext[k * 16 + q] = f2bf(s);
        W1ext[k * 16 + 8 + q] = 0;
      }
    } else if (c == zc + 193) {
      for (int r = 0; r < 2; ++r) {
        int idx = r * 256 + t;
        int k = idx & 255;
        const void* W = (idx < 256) ? W2s_ : W2d_;
        const void* A = (idx < 256) ? a2s_ : a2d_;
        float s = 0.f;
        for (int c2 = 0; c2 < 64; ++c2) s += ldv(W, k * 64 + c2, bf) * ldv(A, c2, bf);
        if (idx < 256) v2s[k] = s; else v2d[k] = s;
      }
    } else {
      b1f[t] = ldv(b1_, t, bf);
      if (t < 64) b2f[t] = ldv(b2_, t, bf);
    }
  }
  gridg.sync();

  // ======== PHASE A2: canonicalize edges + degree histogram ========
  const int ec = cdiv_d(EP, 256);
  for (int c = blockIdx.x; c < ec; c += gridDim.x) {
    int i = c * 256 + t;
    if (i < EP) {
      int s, d;
      if (i < E) {
        if (e64) {
          const unsigned int* p = (const unsigned int*)EI;
          s = (int)p[2 * (size_t)i];
          d = (int)p[2 * ((size_t)E + i)];
        } else {
          const int* p = (const int*)EI;
          s = p[i]; d = p[E + i];
        }
      } else { s = i - E; d = s; }
      if ((unsigned)s >= (unsigned)N) s = 0;
      if ((unsigned)d >= (unsigned)N) d = 0;
      srcI[i] = s; dstI[i] = d;
      atomicAdd(&deg[d], 1);
    }
  }
  gridg.sync();

  // ======== PHASE B: CSR scan (decoupled lookback, single phase) ========
  const int nb = cdiv_d(N, 256);
  if (blockIdx.x < nb) {
    const int c = blockIdx.x;
    int* ssc = (int*)smem;          // [0..255] scan, [256..511] reduce
    int i = c * 256 + t;
    int v = (i < N) ? deg[i] : 0;
    ssc[t] = v;
    __syncthreads();
    for (int off = 1; off < 256; off <<= 1) {
      int add = (t >= off) ? ssc[t - off] : 0;
      __syncthreads();
      ssc[t] += add;
      __syncthreads();
    }
    int incl = ssc[t];
    if (t == 255) atomicExch(&scanflag[c], ssc[255] + 1);  // publish total+1
    __syncthreads();                 // publish precedes any spin (no wave deadlock)
    int pre = 0;
    if (t < c) {
      int f;
      while ((f = atomicAdd(&scanflag[t], 0)) == 0) {}
      pre = f - 1;
    }
    int* s2 = ssc + 256;
    s2[t] = pre;
    __syncthreads();
    for (int off = 128; off; off >>= 1) {
      if (t < off) s2[t] += s2[t + off];
      __syncthreads();
    }
    int preT = s2[0];
    if (i < N) rowst[i] = preT + incl - v;   // exclusive row start
  }
  gridg.sync();

  // ======== PHASE C: fill srcS (CSR adjacency with materialized src) ========
  for (int c = blockIdx.x; c < ec; c += gridDim.x) {
    int i = c * 256 + t;
    if (i < EP) {
      int d = dstI[i];
      int pos = atomicAdd(&cursor[d], 1);
      srcS[rowst[d] + pos] = srcI[i];
    }
  }
  gridg.sync();

  // ======== PHASE D: MFMA GEMM  xs1 = x @ W1 (+ A1 = x @ v1) ========
  {
    const int lane = t & 63, wid = t >> 6;
    const int quad = lane >> 4, m16 = lane & 15;
    const int ntiles = cdiv_d(N, 64);
    unsigned short* Wlds = smem;
    for (int bt = blockIdx.x; bt < ntiles; bt += gridDim.x) {
      __syncthreads();               // smem reuse across grid-stride iterations
      const int r0b = bt * 64;
      const int r0 = r0b + wid * 16;
      const int arow = min(r0 + m16, N - 1);
      short8 af[4];
      if (bf) {
        const uint4* Xr = (const uint4*)((const unsigned int*)X + (size_t)arow * 64);
#pragma unroll
        for (int ks = 0; ks < 4; ++ks)
          af[ks] = __builtin_bit_cast(short8, Xr[ks * 4 + quad]);
      } else {
        const float* Xr = (const float*)X + (size_t)arow * 128;
#pragma unroll
        for (int ks = 0; ks < 4; ++ks) {
          short8 v;
#pragma unroll
          for (int j = 0; j < 8; ++j) v[j] = (short)f2bf(Xr[ks * 32 + quad * 8 + j]);
          af[ks] = v;
        }
      }
      floatx4 accs[9];
      // phase 0: cols 0..127 + A1 tile
      if (t < 144) {
        for (int k0 = 0; k0 < 128; k0 += 4) {
          unsigned int u0, u1;
          if (t < 128) {
            const unsigned short* p = W1c + (size_t)k0 * 256 + t;
            u0 = (unsigned int)p[0] | ((unsigned int)p[256] << 16);
            u1 = (unsigned int)p[512] | ((unsigned int)p[768] << 16);
          } else {
            const unsigned short* p = W1ext + (size_t)k0 * 16 + (t - 128);
            u0 = (unsigned int)p[0] | ((unsigned int)p[16] << 16);
            u1 = (unsigned int)p[32] | ((unsigned int)p[48] << 16);
          }
          *(uint2*)&Wlds[t * 136 + k0] = make_uint2(u0, u1);
        }
      }
      __syncthreads();
#pragma unroll
      for (int ct = 0; ct < 9; ++ct) {
        floatx4 acc = {0.f, 0.f, 0.f, 0.f};
        const unsigned short* wl = &Wlds[(ct * 16 + m16) * 136];
#pragma unroll
        for (int ks = 0; ks < 4; ++ks) {
          short8 bfv = *(const short8*)(wl + ks * 32 + quad * 8);
          acc = __builtin_amdgcn_mfma_f32_16x16x32_bf16(af[ks], bfv, acc, 0, 0, 0);
        }
        accs[ct] = acc;
      }
      __syncthreads();
      if (m16 < 8) {
#pragma unroll
        for (int r = 0; r < 4; ++r) {
          int row = r0 + quad * 4 + r;
          if (row < N) A1[(size_t)row * 8 + m16] = accs[8][r];
        }
      }
#pragma unroll
      for (int ct = 0; ct < 8; ++ct)
#pragma unroll
        for (int r = 0; r < 4; ++r)
          Wlds[(wid * 16 + quad * 4 + r) * 136 + ct * 16 + m16] = f2bf(accs[ct][r]);
      __syncthreads();
#pragma unroll
      for (int it = 0; it < 4; ++it) {
        int lrow = it * 16 + (t >> 4);
        int grow = r0b + lrow;
        if (grow < N) {
          uint4 v = *(const uint4*)&Wlds[lrow * 136 + (t & 15) * 8];
          *(uint4*)(xs1 + (size_t)grow * 256 + (t & 15) * 8) = v;
        }
      }
      __syncthreads();
      // phase 1: cols 128..255
      if (t < 128) {
        for (int k0 = 0; k0 < 128; k0 += 4) {
          const unsigned short* p = W1c + (size_t)k0 * 256 + 128 + t;
          unsigned int u0 = (unsigned int)p[0] | ((unsigned int)p[256] << 16);
          unsigned int u1 = (unsigned int)p[512] | ((unsigned int)p[768] << 16);
          *(uint2*)&Wlds[t * 136 + k0] = make_uint2(u0, u1);
        }
      }
      __syncthreads();
#pragma unroll
      for (int ct = 0; ct < 8; ++ct) {
        floatx4 acc = {0.f, 0.f, 0.f, 0.f};
        const unsigned short* wl = &Wlds[(ct * 16 + m16) * 136];
#pragma unroll
        for (int ks = 0; ks < 4; ++ks) {
          short8 bfv = *(const short8*)(wl + ks * 32 + quad * 8);
          acc = __builtin_amdgcn_mfma_f32_16x16x32_bf16(af[ks], bfv, acc, 0, 0, 0);
        }
        accs[ct] = acc;
      }
      __syncthreads();
#pragma unroll
      for (int ct = 0; ct < 8; ++ct)
#pragma unroll
        for (int r = 0; r < 4; ++r)
          Wlds[(wid * 16 + quad * 4 + r) * 136 + ct * 16 + m16] = f2bf(accs[ct][r]);
      __syncthreads();
#pragma unroll
      for (int it = 0; it < 4; ++it) {
        int lrow = it * 16 + (t >> 4);
        int grow = r0b + lrow;
        if (grow < N) {
          uint4 v = *(const uint4*)&Wlds[lrow * 136 + (t & 15) * 8];
          *(uint4*)(xs1 + (size_t)grow * 256 + 128 + (t & 15) * 8) = v;
        }
      }
    }
  }
  gridg.sync();

  // ======== PHASE E: node1 (softmax+gather, MFMA epilogue) ========
  {
    NodeShm* nsh = (NodeShm*)smem;
    const int lane = t & 63, wid = t >> 6;
    const int ng = cdiv_d(N, 4);
    for (int g = blockIdx.x; g < ng; g += gridDim.x) {
      const int nraw = g * 4 + wid;
      const bool valid = nraw < N;
      const int n = valid ? nraw : (N - 1);
      const int st = rowst[n], dn = deg[n];
      const float4 ad4 = *(const float4*)(A1 + (size_t)n * 8 + 4);
      const float ad[4] = {ad4.x, ad4.y, ad4.z, ad4.w};
      const int gc = 4 * lane;
      const int hL = lane >> 4;
      float acc[4] = {0.f, 0.f, 0.f, 0.f};

      if (dn <= 64) {
        int s = 0;
        float v[4] = {NEG_INF, NEG_INF, NEG_INF, NEG_INF};
        if (lane < dn) {
          s = srcS[st + lane];
          const float4 as4 = *(const float4*)(A1 + (size_t)s * 8);
          const float as[4] = {as4.x, as4.y, as4.z, as4.w};
#pragma unroll
          for (int h = 0; h < 4; ++h) {
            float x = as[h] + ad[h];
            v[h] = x > 0.f ? x : 0.2f * x;
          }
        }
        float m[4], l[4];
#pragma unroll
        for (int h = 0; h < 4; ++h) {
          m[h] = v[h];
#pragma unroll
          for (int off = 32; off; off >>= 1) m[h] = fmaxf(m[h], __shfl_xor(m[h], off));
          float e = (lane < dn) ? __expf(v[h] - m[h]) : 0.f;
          l[h] = e;
#pragma unroll
          for (int off = 32; off; off >>= 1) l[h] += __shfl_xor(l[h], off);
          v[h] = e;
        }
        if (lane < dn) {
          nsh->s_sh[wid][lane] = s;
          float4 al = {v[0] / l[0], v[1] / l[1], v[2] / l[2], v[3] / l[3]};
          *(float4*)&nsh->al_sh[wid][lane][0] = al;
        }
        int j = 0;
        for (; j + 4 <= dn; j += 4) {
          int s0 = nsh->s_sh[wid][j],     s1 = nsh->s_sh[wid][j + 1];
          int s2 = nsh->s_sh[wid][j + 2], s3 = nsh->s_sh[wid][j + 3];
          float a0 = nsh->al_sh[wid][j][hL],     a1 = nsh->al_sh[wid][j + 1][hL];
          float a2 = nsh->al_sh[wid][j + 2][hL], a3 = nsh->al_sh[wid][j + 3][hL];
          uint2 u0 = *(const uint2*)(xs1 + (size_t)s0 * 256 + gc);
          uint2 u1 = *(const uint2*)(xs1 + (size_t)s1 * 256 + gc);
          uint2 u2 = *(const uint2*)(xs1 + (size_t)s2 * 256 + gc);
          uint2 u3 = *(const uint2*)(xs1 + (size_t)s3 * 256 + gc);
          acc[0] += a0 * __uint_as_float(u0.x << 16);
          acc[1] += a0 * __uint_as_float(u0.x & 0xFFFF0000u);
          acc[2] += a0 * __uint_as_float(u0.y << 16);
          acc[3] += a0 * __uint_as_float(u0.y & 0xFFFF0000u);
          acc[0] += a1 * __uint_as_float(u1.x << 16);
          acc[1] += a1 * __uint_as_float(u1.x & 0xFFFF0000u);
          acc[2] += a1 * __uint_as_float(u1.y << 16);
          acc[3] += a1 * __uint_as_float(u1.y & 0xFFFF0000u);
          acc[0] += a2 * __uint_as_float(u2.x << 16);
          acc[1] += a2 * __uint_as_float(u2.x & 0xFFFF0000u);
          acc[2] += a2 * __uint_as_float(u2.y << 16);
          acc[3] += a2 * __uint_as_float(u2.y & 0xFFFF0000u);
          acc[0] += a3 * __uint_as_float(u3.x << 16);
          acc[1] += a3 * __uint_as_float(u3.x & 0xFFFF0000u);
          acc[2] += a3 * __uint_as_float(u3.y << 16);
          acc[3] += a3 * __uint_as_float(u3.y & 0xFFFF0000u);
        }
        for (; j < dn; ++j) {
          int s0 = nsh->s_sh[wid][j];
          float a0 = nsh->al_sh[wid][j][hL];
          uint2 u0 = *(const uint2*)(xs1 + (size_t)s0 * 256 + gc);
          acc[0] += a0 * __uint_as_float(u0.x << 16);
          acc[1] += a0 * __uint_as_float(u0.x & 0xFFFF0000u);
          acc[2] += a0 * __uint_as_float(u0.y << 16);
          acc[3] += a0 * __uint_as_float(u0.y & 0xFFFF0000u);
        }
      } else {
        float m[4] = {NEG_INF, NEG_INF, NEG_INF, NEG_INF};
        for (int j = lane; j < dn; j += 64) {
          int s = srcS[st + j];
          const float4 as4 = *(const float4*)(A1 + (size_t)s * 8);
          const float as[4] = {as4.x, as4.y, as4.z, as4.w};
#pragma unroll
          for (int h = 0; h < 4; ++h) {
            float x = as[h] + ad[h];
            x = x > 0.f ? x : 0.2f * x;
            m[h] = fmaxf(m[h], x);
          }
        }
#pragma unroll
        for (int h = 0; h < 4; ++h)
#pragma unroll
          for (int off = 32; off; off >>= 1) m[h] = fmaxf(m[h], __shfl_xor(m[h], off));
        float l[4] = {0.f, 0.f, 0.f, 0.f};
        for (int j = lane; j < dn; j += 64) {
          int s = srcS[st + j];
          const float4 as4 = *(const float4*)(A1 + (size_t)s * 8);
          const float as[4] = {as4.x, as4.y, as4.z, as4.w};
#pragma unroll
          for (int h = 0; h < 4; ++h) {
            float x = as[h] + ad[h];
            x = x > 0.f ? x : 0.2f * x;
            l[h] += __expf(x - m[h]);
          }
        }
#pragma unroll
        for (int h = 0; h < 4; ++h)
#pragma unroll
          for (int off = 32; off; off >>= 1) l[h] += __shfl_xor(l[h], off);
        const float mh = m[hL], inv = 1.0f / l[hL], adh = ad[hL];
        for (int j = 0; j < dn; ++j) {
          int s = srcS[st + j];
          float x = A1[(size_t)s * 8 + hL] + adh;
          x = x > 0.f ? x : 0.2f * x;
          float alpha = __expf(x - mh) * inv;
          uint2 u = *(const uint2*)(xs1 + (size_t)s * 256 + gc);
          acc[0] += alpha * __uint_as_float(u.x << 16);
          acc[1] += alpha * __uint_as_float(u.x & 0xFFFF0000u);
          acc[2] += alpha * __uint_as_float(u.y << 16);
          acc[3] += alpha * __uint_as_float(u.y & 0xFFFF0000u);
        }
      }

      const float4 bb = *(const float4*)(b1f + gc);
      float h0 = acc[0] + bb.x, h1 = acc[1] + bb.y;
      float h2 = acc[2] + bb.z, h3 = acc[3] + bb.w;
      h0 = h0 > 0.f ? h0 : 0.f; h1 = h1 > 0.f ? h1 : 0.f;
      h2 = h2 > 0.f ? h2 : 0.f; h3 = h3 > 0.f ? h3 : 0.f;
      const float4 vs = *(const float4*)(v2s + gc);
      const float4 vd = *(const float4*)(v2d + gc);
      float ps = h0 * vs.x + h1 * vs.y + h2 * vs.z + h3 * vs.w;
      float pd = h0 * vd.x + h1 * vd.y + h2 * vd.z + h3 * vd.w;
#pragma unroll
      for (int off = 1; off <= 32; off <<= 1) {
        ps += __shfl_xor(ps, off);
        pd += __shfl_xor(pd, off);
      }
      unsigned int p0 = (unsigned int)f2bf(h0) | ((unsigned int)f2bf(h1) << 16);
      unsigned int p1 = (unsigned int)f2bf(h2) | ((unsigned int)f2bf(h3) << 16);
      *(uint2*)&nsh->hb[wid][gc] = make_uint2(p0, p1);
      if (valid && lane == 0) {
        A2b[(size_t)n * 2] = ps;
        A2b[(size_t)n * 2 + 1] = pd;
      }
      __syncthreads();
      // block MFMA: wave wid -> 16-col tile of xs2 = h(4x256) @ W2s(256x64)
      const int m16 = lane & 15, quad = lane >> 4;
      floatx4 c2 = {0.f, 0.f, 0.f, 0.f};
      const unsigned short* arow = &nsh->hb[m16 & 3][0];
      const unsigned short* bcol = W2sT + (size_t)(wid * 16 + m16) * 256;
#pragma unroll
      for (int ks = 0; ks < 8; ++ks) {
        short8 afr = *(const short8*)(arow + ks * 32 + quad * 8);
        short8 bfr = *(const short8*)(bcol + ks * 32 + quad * 8);
        c2 = __builtin_amdgcn_mfma_f32_16x16x32_bf16(afr, bfr, c2, 0, 0, 0);
      }
      if (quad == 0) {
#pragma unroll
        for (int r = 0; r < 4; ++r) {
          int node = g * 4 + r;
          if (node < N) xs2[(size_t)node * 64 + wid * 16 + m16] = f2bf(c2[r]);
        }
      }
      __syncthreads();               // protect hb before next iteration
    }
  }
  gridg.sync();

  // ======== PHASE F: node2 -> output ========
  {
    NodeShm* nsh = (NodeShm*)smem;
    const int lane = t & 63, wid = t >> 6;
    const int ng = cdiv_d(N, 4);
    for (int g = blockIdx.x; g < ng; g += gridDim.x) {
      const int n = g * 4 + wid;
      if (n >= N) continue;          // per-wave work only, no block barriers
      const int st = rowst[n], dn = deg[n];
      const float ad = A2b[(size_t)n * 2 + 1];
      float acc = 0.f;
      int* s_sh = nsh->s_sh[wid];
      float* al_sh = &nsh->al_sh[wid][0][0];
      if (dn <= 64) {
        int s = 0; float v = NEG_INF;
        if (lane < dn) {
          s = srcS[st + lane];
          v = A2b[(size_t)s * 2] + ad;
          v = v > 0.f ? v : 0.2f * v;
        }
        float m = v;
#pragma unroll
        for (int off = 32; off; off >>= 1) m = fmaxf(m, __shfl_xor(m, off));
        float e = (lane < dn) ? __expf(v - m) : 0.f;
        float l = e;
#pragma unroll
        for (int off = 32; off; off >>= 1) l += __shfl_xor(l, off);
        if (lane < dn) { s_sh[lane] = s; al_sh[lane] = e / l; }
        int j = 0;
        for (; j + 4 <= dn; j += 4) {
          int s0 = s_sh[j], s1 = s_sh[j + 1], s2 = s_sh[j + 2], s3 = s_sh[j + 3];
          float a0 = al_sh[j], a1 = al_sh[j + 1], a2 = al_sh[j + 2], a3 = al_sh[j + 3];
          float x0 = bf2f(xs2[(size_t)s0 * 64 + lane]);
          float x1 = bf2f(xs2[(size_t)s1 * 64 + lane]);
          float x2 = bf2f(xs2[(size_t)s2 * 64 + lane]);
          float x3 = bf2f(xs2[(size_t)s3 * 64 + lane]);
          acc += a0 * x0 + a1 * x1 + a2 * x2 + a3 * x3;
        }
        for (; j < dn; ++j)
          acc += al_sh[j] * bf2f(xs2[(size_t)s_sh[j] * 64 + lane]);
      } else {
        float m = NEG_INF;
        for (int j = lane; j < dn; j += 64) {
          int s = srcS[st + j];
          float v = A2b[(size_t)s * 2] + ad;
          v = v > 0.f ? v : 0.2f * v;
          m = fmaxf(m, v);
        }
#pragma unroll
        for (int off = 32; off; off >>= 1) m = fmaxf(m, __shfl_xor(m, off));
        float l = 0.f;
        for (int j = lane; j < dn; j += 64) {
          int s = srcS[st + j];
          float v = A2b[(size_t)s * 2] + ad;
          v = v > 0.f ? v : 0.2f * v;
          l += __expf(v - m);
        }
#pragma unroll
        for (int off = 32; off; off >>= 1) l += __shfl_xor(l, off);
        float inv = 1.0f / l;
        for (int j = 0; j < dn; ++j) {
          int s = srcS[st + j];
          float v = A2b[(size_t)s * 2] + ad;
          v = v > 0.f ? v : 0.2f * v;
          acc += __expf(v - m) * inv * bf2f(xs2[(size_t)s * 64 + lane]);
        }
      }
      out[(size_t)n * 64 + lane] = acc + b2f[lane];
    }
  }
}

extern "C" void kernel_launch(void* const* d_in, const int* in_sizes, int n_in,
                              void* d_out, int out_size, void* d_ws, size_t ws_size,
                              hipStream_t stream) {
  const int N = in_sizes[0] / 128;
  const int E = in_sizes[1] / 2;
  (void)n_in;

  const WS L = ws_layout(N, E);
  if (ws_size < L.need) {  // canary: report ws MB via output
    fill_out_kernel<<<cdiv(out_size, 256), 256, 0, stream>>>(
        (float*)d_out, out_size, 131072.0f + 1024.0f * (float)(ws_size >> 20));
    return;
  }

  // co-resident grid size from occupancy (expect 4 blocks/CU via 39KB LDS)
  int blocksPerCU = 0;
  hipOccupancyMaxActiveBlocksPerMultiprocessor(&blocksPerCU, mega, 256, 0);
  int nCU = 256;
  {
    int dev = 0;
    hipDeviceProp_t prop;
    if (hipGetDevice(&dev) == hipSuccess &&
        hipGetDeviceProperties(&prop, dev) == hipSuccess)
      nCU = prop.multiProcessorCount;
  }
  if (blocksPerCU < 1) blocksPerCU = 1;
  int grid = blocksPerCU * nCU;
  const int nb = cdiv(N, 256);
  if (grid < nb) grid = nb;          // scan needs >= nb blocks
  if (grid > 4096) grid = 4096;

  const void* X   = d_in[0];
  const void* EI  = d_in[1];
  const void* W1s = d_in[2];
  const void* W1d = d_in[3];
  const void* a1s = d_in[4];
  const void* a1d = d_in[5];
  const void* b1  = d_in[6];
  const void* W2s = d_in[7];
  const void* W2d = d_in[8];
  const void* a2s = d_in[9];
  const void* a2d = d_in[10];
  const void* b2  = d_in[11];
  char* wsp = (char*)d_ws;
  float* outp = (float*)d_out;
  int Na = N, Ea = E;
  void* args[] = {&X, &EI, &W1s, &W1d, &a1s, &a1d, &W2s, &W2d, &a2s, &a2d,
                  &b1, &b2, &wsp, &outp, &Na, &Ea};
  hipLaunchCooperativeKernel((const void*)mega, dim3(grid), dim3(256),
                             args, 0, stream);
}

// Round 12
// 336.189 us; speedup vs baseline: 2.7100x; 2.7100x over previous
//
#include <hip/hip_runtime.h>

// ---------------------------------------------------------------------------
// GAT 2-layer forward (N=50k, F=128, L1: H=4 x 64, L2: 1 x 64), MI355X.
// Round 12: REVERT cooperative mega-kernel (R11: grid.sync + spin atomics ->
// 405MB write traffic, 911us). Back to R10 structure, consolidated 8->5
// dispatches by fusing INDEPENDENT phases (block-role branching, no sync):
//   memset | K1 = weight-prep || edge-canon+deg | K2 = CSR lookback-scan ||
//   MFMA gemm | K3 fill_srcS | K4 node1 | K5 node2.
// ---------------------------------------------------------------------------

static inline int cdiv(int a, int b) { return (a + b - 1) / b; }

typedef __attribute__((ext_vector_type(8))) short short8;
typedef __attribute__((ext_vector_type(4))) float floatx4;

__device__ __forceinline__ float bf2f(unsigned short u) {
  return __uint_as_float(((unsigned int)u) << 16);
}
__device__ __forceinline__ unsigned short f2bf(float f) {  // RNE
  unsigned int u = __float_as_uint(f);
  unsigned int r = (u + 0x7FFFu + ((u >> 16) & 1u)) >> 16;
  return (unsigned short)r;
}
__device__ __forceinline__ float ldv(const void* p, int i, int bf) {
  return bf ? bf2f(((const unsigned short*)p)[i]) : ((const float*)p)[i];
}
#define NEG_INF (-__builtin_inff())

__global__ void fill_out_kernel(float* __restrict__ out, int n, float val) {
  int t = blockIdx.x * blockDim.x + threadIdx.x;
  if (t < n) out[t] = val;
}

// per-block dtype probes (deterministic -> all blocks agree)
__device__ void block_probes(const unsigned short* xu, const unsigned int* eu,
                             int& bf, int& e64) {
  __shared__ int cc, ce;
  if (threadIdx.x == 0) { cc = 0; ce = 0; }
  __syncthreads();
  int l0 = 0, l1 = 0;
  for (int i = threadIdx.x; i < 1024; i += 256) {
    int e = (xu[2 * i] >> 7) & 0xFF;
    if (e >= 100 && e <= 141) l0++;
    if (eu[2 * i + 1] == 0u) l1++;
  }
  atomicAdd(&cc, l0); atomicAdd(&ce, l1);
  __syncthreads();
  bf = cc > 512 ? 1 : 0;
  e64 = ce > 512 ? 1 : 0;
}

// K1: weight prep (blocks 0..194) || edge canon + degree (blocks 195..)
// deg/cursor/scanflag pre-zeroed by hipMemsetAsync (stream-ordered).
__global__ void prep_edges(const unsigned short* __restrict__ xu,
                           const void* __restrict__ EI, int E, int EP, int Nn,
                           const void* __restrict__ W1s, const void* __restrict__ W1d,
                           const void* __restrict__ a1s, const void* __restrict__ a1d,
                           const void* __restrict__ W2s, const void* __restrict__ W2d,
                           const void* __restrict__ a2s, const void* __restrict__ a2d,
                           const void* __restrict__ b1, const void* __restrict__ b2,
                           unsigned short* __restrict__ W1c,
                           unsigned short* __restrict__ W2sT,
                           unsigned short* __restrict__ W1ext,
                           float* __restrict__ v2s, float* __restrict__ v2d,
                           float* __restrict__ b1f, float* __restrict__ b2f,
                           int* __restrict__ srcI, int* __restrict__ dstI,
                           int* __restrict__ deg) {
  const int b = blockIdx.x, t = threadIdx.x;
  int bf, e64;
  block_probes(xu, (const unsigned int*)EI, bf, e64);
  if (b < 128) {
    int i = b * 256 + t;
    W1c[i] = f2bf(ldv(W1s, i, bf));
  } else if (b < 192) {
    int i = (b - 128) * 256 + t;
    int k = i >> 6, col = i & 63;
    W2sT[col * 256 + k] = f2bf(ldv(W2s, i, bf));
  } else if (b == 192) {
    for (int r = 0; r < 4; ++r) {
      int idx = r * 256 + t;
      int k = idx >> 3, q = idx & 7, h = q & 3;
      const void* W = (q < 4) ? W1s : W1d;
      const void* A = (q < 4) ? a1s : a1d;
      float s = 0.f;
      for (int c = 0; c < 64; ++c)
        s += ldv(W, k * 256 + h * 64 + c, bf) * ldv(A, h * 64 + c, bf);
      W1ext[k * 16 + q] = f2bf(s);
      W1ext[k * 16 + 8 + q] = 0;
    }
  } else if (b == 193) {
    for (int r = 0; r < 2; ++r) {
      int idx = r * 256 + t;
      int k = idx & 255;
      const void* W = (idx < 256) ? W2s : W2d;
      const void* A = (idx < 256) ? a2s : a2d;
      float s = 0.f;
      for (int c = 0; c < 64; ++c) s += ldv(W, k * 64 + c, bf) * ldv(A, c, bf);
      if (idx < 256) v2s[k] = s; else v2d[k] = s;
    }
  } else if (b == 194) {
    b1f[t] = ldv(b1, t, bf);
    if (t < 64) b2f[t] = ldv(b2, t, bf);
  } else {
    int i = (b - 195) * 256 + t;
    if (i < EP) {
      int s, d;
      if (i < E) {
        if (e64) {
          const unsigned int* p = (const unsigned int*)EI;
          s = (int)p[2 * (size_t)i];
          d = (int)p[2 * ((size_t)E + i)];
        } else {
          const int* p = (const int*)EI;
          s = p[i]; d = p[E + i];
        }
      } else { s = i - E; d = s; }
      if ((unsigned)s >= (unsigned)Nn) s = 0;
      if ((unsigned)d >= (unsigned)Nn) d = 0;
      srcI[i] = s; dstI[i] = d;
      atomicAdd(&deg[d], 1);
    }
  }
}

// K2: blocks [0,nb) = CSR scan (decoupled lookback, correctness-proven R11);
//     blocks [nb,..) = MFMA GEMM xs1 = x @ W1 (+ A1 = x @ v1 tile).
// All blocks co-resident (978 <= 1024 at 4 blocks/CU) -> spin is safe.
__global__ __launch_bounds__(256) void scan_gemm(
    const void* __restrict__ X, const unsigned short* __restrict__ xu,
    const int* __restrict__ deg, int* __restrict__ rowst,
    int* __restrict__ scanflag, int nb,
    const unsigned short* __restrict__ W1c, const unsigned short* __restrict__ W1ext,
    unsigned short* __restrict__ xs1, float* __restrict__ A1, int N) {
  __shared__ __align__(16) unsigned short smem[9 * 16 * 136];
  const int t = threadIdx.x;
  if (blockIdx.x < nb) {
    // ---- CSR scan ----
    const int c = blockIdx.x;
    int* ssc = (int*)smem;
    int i = c * 256 + t;
    int v = (i < N) ? deg[i] : 0;
    ssc[t] = v;
    __syncthreads();
    for (int off = 1; off < 256; off <<= 1) {
      int add = (t >= off) ? ssc[t - off] : 0;
      __syncthreads();
      ssc[t] += add;
      __syncthreads();
    }
    int incl = ssc[t];
    if (t == 255) atomicExch(&scanflag[c], ssc[255] + 1);  // publish total+1
    __syncthreads();
    int pre = 0;
    if (t < c) {
      int f;
      while ((f = atomicAdd(&scanflag[t], 0)) == 0) {}
      pre = f - 1;
    }
    int* s2 = ssc + 256;
    s2[t] = pre;
    __syncthreads();
    for (int off = 128; off; off >>= 1) {
      if (t < off) s2[t] += s2[t + off];
      __syncthreads();
    }
    if (i < N) rowst[i] = s2[0] + incl - v;  // exclusive row start
    return;
  }
  // ---- MFMA GEMM tile ----
  __shared__ int pcc;
  if (t == 0) pcc = 0;
  __syncthreads();
  {
    int l0 = 0;
    for (int i = t; i < 1024; i += 256) {
      int e = (xu[2 * i] >> 7) & 0xFF;
      if (e >= 100 && e <= 141) l0++;
    }
    atomicAdd(&pcc, l0);
  }
  __syncthreads();
  const int bf = pcc > 512 ? 1 : 0;
  unsigned short* Wlds = smem;
  const int lane = t & 63, wid = t >> 6;
  const int quad = lane >> 4, m16 = lane & 15;
  const int r0b = (blockIdx.x - nb) * 64;
  const int r0 = r0b + wid * 16;
  const int arow = min(r0 + m16, N - 1);
  short8 af[4];
  if (bf) {
    const uint4* Xr = (const uint4*)((const unsigned int*)X + (size_t)arow * 64);
#pragma unroll
    for (int ks = 0; ks < 4; ++ks)
      af[ks] = __builtin_bit_cast(short8, Xr[ks * 4 + quad]);
  } else {
    const float* Xr = (const float*)X + (size_t)arow * 128;
#pragma unroll
    for (int ks = 0; ks < 4; ++ks) {
      short8 v;
#pragma unroll
      for (int j = 0; j < 8; ++j) v[j] = (short)f2bf(Xr[ks * 32 + quad * 8 + j]);
      af[ks] = v;
    }
  }
  floatx4 accs[9];
  // phase 0: cols 0..127 + A1 tile
  if (t < 144) {
    for (int k0 = 0; k0 < 128; k0 += 4) {
      unsigned int u0, u1;
      if (t < 128) {
        const unsigned short* p = W1c + (size_t)k0 * 256 + t;
        u0 = (unsigned int)p[0] | ((unsigned int)p[256] << 16);
        u1 = (unsigned int)p[512] | ((unsigned int)p[768] << 16);
      } else {
        const unsigned short* p = W1ext + (size_t)k0 * 16 + (t - 128);
        u0 = (unsigned int)p[0] | ((unsigned int)p[16] << 16);
        u1 = (unsigned int)p[32] | ((unsigned int)p[48] << 16);
      }
      *(uint2*)&Wlds[t * 136 + k0] = make_uint2(u0, u1);
    }
  }
  __syncthreads();
#pragma unroll
  for (int ct = 0; ct < 9; ++ct) {
    floatx4 acc = {0.f, 0.f, 0.f, 0.f};
    const unsigned short* wl = &Wlds[(ct * 16 + m16) * 136];
#pragma unroll
    for (int ks = 0; ks < 4; ++ks) {
      short8 bfv = *(const short8*)(wl + ks * 32 + quad * 8);
      acc = __builtin_amdgcn_mfma_f32_16x16x32_bf16(af[ks], bfv, acc, 0, 0, 0);
    }
    accs[ct] = acc;
  }
  __syncthreads();
  if (m16 < 8) {
#pragma unroll
    for (int r = 0; r < 4; ++r) {
      int row = r0 + quad * 4 + r;
      if (row < N) A1[(size_t)row * 8 + m16] = accs[8][r];
    }
  }
#pragma unroll
  for (int ct = 0; ct < 8; ++ct)
#pragma unroll
    for (int r = 0; r < 4; ++r)
      Wlds[(wid * 16 + quad * 4 + r) * 136 + ct * 16 + m16] = f2bf(accs[ct][r]);
  __syncthreads();
#pragma unroll
  for (int it = 0; it < 4; ++it) {
    int lrow = it * 16 + (t >> 4);
    int grow = r0b + lrow;
    if (grow < N) {
      uint4 v = *(const uint4*)&Wlds[lrow * 136 + (t & 15) * 8];
      *(uint4*)(xs1 + (size_t)grow * 256 + (t & 15) * 8) = v;
    }
  }
  __syncthreads();
  // phase 1: cols 128..255
  if (t < 128) {
    for (int k0 = 0; k0 < 128; k0 += 4) {
      const unsigned short* p = W1c + (size_t)k0 * 256 + 128 + t;
      unsigned int u0 = (unsigned int)p[0] | ((unsigned int)p[256] << 16);
      unsigned int u1 = (unsigned int)p[512] | ((unsigned int)p[768] << 16);
      *(uint2*)&Wlds[t * 136 + k0] = make_uint2(u0, u1);
    }
  }
  __syncthreads();
#pragma unroll
  for (int ct = 0; ct < 8; ++ct) {
    floatx4 acc = {0.f, 0.f, 0.f, 0.f};
    const unsigned short* wl = &Wlds[(ct * 16 + m16) * 136];
#pragma unroll
    for (int ks = 0; ks < 4; ++ks) {
      short8 bfv = *(const short8*)(wl + ks * 32 + quad * 8);
      acc = __builtin_amdgcn_mfma_f32_16x16x32_bf16(af[ks], bfv, acc, 0, 0, 0);
    }
    accs[ct] = acc;
  }
  __syncthreads();
#pragma unroll
  for (int ct = 0; ct < 8; ++ct)
#pragma unroll
    for (int r = 0; r < 4; ++r)
      Wlds[(wid * 16 + quad * 4 + r) * 136 + ct * 16 + m16] = f2bf(accs[ct][r]);
  __syncthreads();
#pragma unroll
  for (int it = 0; it < 4; ++it) {
    int lrow = it * 16 + (t >> 4);
    int grow = r0b + lrow;
    if (grow < N) {
      uint4 v = *(const uint4*)&Wlds[lrow * 136 + (t & 15) * 8];
      *(uint4*)(xs1 + (size_t)grow * 256 + 128 + (t & 15) * 8) = v;
    }
  }
}

// K3: CSR fill with materialized src node ids
__global__ void fill_srcS(const int* __restrict__ srcI, const int* __restrict__ dstI,
                          int EP, const int* __restrict__ rowst,
                          int* __restrict__ cursor, int* __restrict__ srcS) {
  int t = blockIdx.x * blockDim.x + threadIdx.x;
  if (t >= EP) return;
  int d = dstI[t];
  int pos = atomicAdd(&cursor[d], 1);
  srcS[rowst[d] + pos] = srcI[t];
}

// K4: node1 softmax+gather (4 heads) + block-MFMA epilogue xs2 = h @ W2s.
__global__ __launch_bounds__(256) void node1_merged(
    const int* __restrict__ rowst, const int* __restrict__ deg,
    const int* __restrict__ srcS,
    const float* __restrict__ A1, const unsigned short* __restrict__ xs1,
    const float* __restrict__ b1f, const unsigned short* __restrict__ W2sT,
    const float* __restrict__ v2s, const float* __restrict__ v2d,
    unsigned short* __restrict__ xs2, float* __restrict__ A2, int N) {
  __shared__ unsigned short hb[4][272];
  __shared__ int   s_sh[4][64];
  __shared__ float al_sh[4][64][4];
  const int lane = threadIdx.x & 63;
  const int wid = threadIdx.x >> 6;
  const int nraw = blockIdx.x * 4 + wid;
  const bool valid = nraw < N;
  const int n = valid ? nraw : (N - 1);
  const int st = rowst[n], dn = deg[n];
  const float4 ad4 = *(const float4*)(A1 + (size_t)n * 8 + 4);
  const float ad[4] = {ad4.x, ad4.y, ad4.z, ad4.w};
  const int gc = 4 * lane;
  const int hL = lane >> 4;
  float acc[4] = {0.f, 0.f, 0.f, 0.f};

  if (dn <= 64) {
    int s = 0;
    float v[4] = {NEG_INF, NEG_INF, NEG_INF, NEG_INF};
    if (lane < dn) {
      s = srcS[st + lane];
      const float4 as4 = *(const float4*)(A1 + (size_t)s * 8);
      const float as[4] = {as4.x, as4.y, as4.z, as4.w};
#pragma unroll
      for (int h = 0; h < 4; ++h) {
        float x = as[h] + ad[h];
        v[h] = x > 0.f ? x : 0.2f * x;
      }
    }
    float m[4], l[4];
#pragma unroll
    for (int h = 0; h < 4; ++h) {
      m[h] = v[h];
#pragma unroll
      for (int off = 32; off; off >>= 1) m[h] = fmaxf(m[h], __shfl_xor(m[h], off));
      float e = (lane < dn) ? __expf(v[h] - m[h]) : 0.f;
      l[h] = e;
#pragma unroll
      for (int off = 32; off; off >>= 1) l[h] += __shfl_xor(l[h], off);
      v[h] = e;
    }
    if (lane < dn) {
      s_sh[wid][lane] = s;
      float4 al = {v[0] / l[0], v[1] / l[1], v[2] / l[2], v[3] / l[3]};
      *(float4*)&al_sh[wid][lane][0] = al;
    }
    int j = 0;
    for (; j + 4 <= dn; j += 4) {
      int s0 = s_sh[wid][j], s1 = s_sh[wid][j + 1];
      int s2 = s_sh[wid][j + 2], s3 = s_sh[wid][j + 3];
      float a0 = al_sh[wid][j][hL],     a1 = al_sh[wid][j + 1][hL];
      float a2 = al_sh[wid][j + 2][hL], a3 = al_sh[wid][j + 3][hL];
      uint2 u0 = *(const uint2*)(xs1 + (size_t)s0 * 256 + gc);
      uint2 u1 = *(const uint2*)(xs1 + (size_t)s1 * 256 + gc);
      uint2 u2 = *(const uint2*)(xs1 + (size_t)s2 * 256 + gc);
      uint2 u3 = *(const uint2*)(xs1 + (size_t)s3 * 256 + gc);
      acc[0] += a0 * __uint_as_float(u0.x << 16);
      acc[1] += a0 * __uint_as_float(u0.x & 0xFFFF0000u);
      acc[2] += a0 * __uint_as_float(u0.y << 16);
      acc[3] += a0 * __uint_as_float(u0.y & 0xFFFF0000u);
      acc[0] += a1 * __uint_as_float(u1.x << 16);
      acc[1] += a1 * __uint_as_float(u1.x & 0xFFFF0000u);
      acc[2] += a1 * __uint_as_float(u1.y << 16);
      acc[3] += a1 * __uint_as_float(u1.y & 0xFFFF0000u);
      acc[0] += a2 * __uint_as_float(u2.x << 16);
      acc[1] += a2 * __uint_as_float(u2.x & 0xFFFF0000u);
      acc[2] += a2 * __uint_as_float(u2.y << 16);
      acc[3] += a2 * __uint_as_float(u2.y & 0xFFFF0000u);
      acc[0] += a3 * __uint_as_float(u3.x << 16);
      acc[1] += a3 * __uint_as_float(u3.x & 0xFFFF0000u);
      acc[2] += a3 * __uint_as_float(u3.y << 16);
      acc[3] += a3 * __uint_as_float(u3.y & 0xFFFF0000u);
    }
    for (; j < dn; ++j) {
      int s0 = s_sh[wid][j];
      float a0 = al_sh[wid][j][hL];
      uint2 u0 = *(const uint2*)(xs1 + (size_t)s0 * 256 + gc);
      acc[0] += a0 * __uint_as_float(u0.x << 16);
      acc[1] += a0 * __uint_as_float(u0.x & 0xFFFF0000u);
      acc[2] += a0 * __uint_as_float(u0.y << 16);
      acc[3] += a0 * __uint_as_float(u0.y & 0xFFFF0000u);
    }
  } else {
    float m[4] = {NEG_INF, NEG_INF, NEG_INF, NEG_INF};
    for (int j = lane; j < dn; j += 64) {
      int s = srcS[st + j];
      const float4 as4 = *(const float4*)(A1 + (size_t)s * 8);
      const float as[4] = {as4.x, as4.y, as4.z, as4.w};
#pragma unroll
      for (int h = 0; h < 4; ++h) {
        float x = as[h] + ad[h];
        x = x > 0.f ? x : 0.2f * x;
        m[h] = fmaxf(m[h], x);
      }
    }
#pragma unroll
    for (int h = 0; h < 4; ++h)
#pragma unroll
      for (int off = 32; off; off >>= 1) m[h] = fmaxf(m[h], __shfl_xor(m[h], off));
    float l[4] = {0.f, 0.f, 0.f, 0.f};
    for (int j = lane; j < dn; j += 64) {
      int s = srcS[st + j];
      const float4 as4 = *(const float4*)(A1 + (size_t)s * 8);
      const float as[4] = {as4.x, as4.y, as4.z, as4.w};
#pragma unroll
      for (int h = 0; h < 4; ++h) {
        float x = as[h] + ad[h];
        x = x > 0.f ? x : 0.2f * x;
        l[h] += __expf(x - m[h]);
      }
    }
#pragma unroll
    for (int h = 0; h < 4; ++h)
#pragma unroll
      for (int off = 32; off; off >>= 1) l[h] += __shfl_xor(l[h], off);
    const float mh = m[hL], inv = 1.0f / l[hL], adh = ad[hL];
    for (int j = 0; j < dn; ++j) {
      int s = srcS[st + j];
      float x = A1[(size_t)s * 8 + hL] + adh;
      x = x > 0.f ? x : 0.2f * x;
      float alpha = __expf(x - mh) * inv;
      uint2 u = *(const uint2*)(xs1 + (size_t)s * 256 + gc);
      acc[0] += alpha * __uint_as_float(u.x << 16);
      acc[1] += alpha * __uint_as_float(u.x & 0xFFFF0000u);
      acc[2] += alpha * __uint_as_float(u.y << 16);
      acc[3] += alpha * __uint_as_float(u.y & 0xFFFF0000u);
    }
  }

  const float4 bb = *(const float4*)(b1f + gc);
  float h0 = acc[0] + bb.x, h1 = acc[1] + bb.y;
  float h2 = acc[2] + bb.z, h3 = acc[3] + bb.w;
  h0 = h0 > 0.f ? h0 : 0.f; h1 = h1 > 0.f ? h1 : 0.f;
  h2 = h2 > 0.f ? h2 : 0.f; h3 = h3 > 0.f ? h3 : 0.f;
  const float4 vs = *(const float4*)(v2s + gc);
  const float4 vd = *(const float4*)(v2d + gc);
  float ps = h0 * vs.x + h1 * vs.y + h2 * vs.z + h3 * vs.w;
  float pd = h0 * vd.x + h1 * vd.y + h2 * vd.z + h3 * vd.w;
#pragma unroll
  for (int off = 1; off <= 32; off <<= 1) {
    ps += __shfl_xor(ps, off);
    pd += __shfl_xor(pd, off);
  }
  unsigned int p0 = (unsigned int)f2bf(h0) | ((unsigned int)f2bf(h1) << 16);
  unsigned int p1 = (unsigned int)f2bf(h2) | ((unsigned int)f2bf(h3) << 16);
  *(uint2*)&hb[wid][gc] = make_uint2(p0, p1);
  if (valid && lane == 0) {
    A2[(size_t)n * 2] = ps;
    A2[(size_t)n * 2 + 1] = pd;
  }
  __syncthreads();
  const int m16 = lane & 15, quad = lane >> 4;
  floatx4 c2 = {0.f, 0.f, 0.f, 0.f};
  const unsigned short* arow = &hb[m16 & 3][0];
  const unsigned short* bcol = W2sT + (size_t)(wid * 16 + m16) * 256;
#pragma unroll
  for (int ks = 0; ks < 8; ++ks) {
    short8 afr = *(const short8*)(arow + ks * 32 + quad * 8);
    short8 bfr = *(const short8*)(bcol + ks * 32 + quad * 8);
    c2 = __builtin_amdgcn_mfma_f32_16x16x32_bf16(afr, bfr, c2, 0, 0, 0);
  }
  if (quad == 0) {
#pragma unroll
    for (int r = 0; r < 4; ++r) {
      int node = blockIdx.x * 4 + r;
      if (node < N) xs2[(size_t)node * 64 + wid * 16 + m16] = f2bf(c2[r]);
    }
  }
}

// K5: layer-2 aggregation -> f32 output
__global__ __launch_bounds__(256) void node2(const int* __restrict__ rowst,
    const int* __restrict__ deg, const int* __restrict__ srcS,
    const float* __restrict__ A2, const unsigned short* __restrict__ xs2,
    const float* __restrict__ b2f, float* __restrict__ out, int N) {
  __shared__ int   s_sh[4][64];
  __shared__ float al_sh[4][64];
  const int lane = threadIdx.x & 63;
  const int wid = threadIdx.x >> 6;
  const int n = blockIdx.x * 4 + wid;
  if (n >= N) return;  // wave-uniform
  const int st = rowst[n], dn = deg[n];
  const float ad = A2[(size_t)n * 2 + 1];
  float acc = 0.f;
  if (dn <= 64) {
    int s = 0; float v = NEG_INF;
    if (lane < dn) {
      s = srcS[st + lane];
      v = A2[(size_t)s * 2] + ad;
      v = v > 0.f ? v : 0.2f * v;
    }
    float m = v;
#pragma unroll
    for (int off = 32; off; off >>= 1) m = fmaxf(m, __shfl_xor(m, off));
    float e = (lane < dn) ? __expf(v - m) : 0.f;
    float l = e;
#pragma unroll
    for (int off = 32; off; off >>= 1) l += __shfl_xor(l, off);
    if (lane < dn) { s_sh[wid][lane] = s; al_sh[wid][lane] = e / l; }
    int j = 0;
    for (; j + 4 <= dn; j += 4) {
      int s0 = s_sh[wid][j], s1 = s_sh[wid][j + 1];
      int s2 = s_sh[wid][j + 2], s3 = s_sh[wid][j + 3];
      float a0 = al_sh[wid][j],     a1 = al_sh[wid][j + 1];
      float a2 = al_sh[wid][j + 2], a3 = al_sh[wid][j + 3];
      float x0 = bf2f(xs2[(size_t)s0 * 64 + lane]);
      float x1 = bf2f(xs2[(size_t)s1 * 64 + lane]);
      float x2 = bf2f(xs2[(size_t)s2 * 64 + lane]);
      float x3 = bf2f(xs2[(size_t)s3 * 64 + lane]);
      acc += a0 * x0 + a1 * x1 + a2 * x2 + a3 * x3;
    }
    for (; j < dn; ++j)
      acc += al_sh[wid][j] * bf2f(xs2[(size_t)s_sh[wid][j] * 64 + lane]);
  } else {
    float m = NEG_INF;
    for (int j = lane; j < dn; j += 64) {
      int s = srcS[st + j];
      float v = A2[(size_t)s * 2] + ad;
      v = v > 0.f ? v : 0.2f * v;
      m = fmaxf(m, v);
    }
#pragma unroll
    for (int off = 32; off; off >>= 1) m = fmaxf(m, __shfl_xor(m, off));
    float l = 0.f;
    for (int j = lane; j < dn; j += 64) {
      int s = srcS[st + j];
      float v = A2[(size_t)s * 2] + ad;
      v = v > 0.f ? v : 0.2f * v;
      l += __expf(v - m);
    }
#pragma unroll
    for (int off = 32; off; off >>= 1) l += __shfl_xor(l, off);
    float inv = 1.0f / l;
    for (int j = 0; j < dn; ++j) {
      int s = srcS[st + j];
      float v = A2[(size_t)s * 2] + ad;
      v = v > 0.f ? v : 0.2f * v;
      acc += __expf(v - m) * inv * bf2f(xs2[(size_t)s * 64 + lane]);
    }
  }
  out[(size_t)n * 64 + lane] = acc + b2f[lane];
}

extern "C" void kernel_launch(void* const* d_in, const int* in_sizes, int n_in,
                              void* d_out, int out_size, void* d_ws, size_t ws_size,
                              hipStream_t stream) {
  const int F = 128, HC1 = 256, C2 = 64;
  const int N  = in_sizes[0] / F;
  const int E  = in_sizes[1] / 2;
  const int EP = E + N;
  (void)n_in;

  char* w = (char*)d_ws;
  size_t off = 0;
  auto alloc = [&](size_t bytes) -> char* {
    char* p = w + off;
    off = (off + bytes + 255) & ~(size_t)255;
    return p;
  };
  int* srcI   = (int*)alloc((size_t)EP * 4);
  int* dstI   = (int*)alloc((size_t)EP * 4);
  int* degcur = (int*)alloc(((size_t)2 * N + 256) * 4);  // deg|cursor|scanflag
  int* deg    = degcur;
  int* cursor = degcur + N;
  int* scanflag = degcur + 2 * N;
  int* rowst  = (int*)alloc((size_t)N * 4);
  unsigned short* W1c   = (unsigned short*)alloc((size_t)F * HC1 * 2);
  unsigned short* W1ext = (unsigned short*)alloc(128 * 16 * 2);
  unsigned short* W2sT  = (unsigned short*)alloc((size_t)HC1 * C2 * 2);
  float* v2s  = (float*)alloc(256 * 4);
  float* v2d  = (float*)alloc(256 * 4);
  float* b1f  = (float*)alloc(256 * 4);
  float* b2f  = (float*)alloc(64 * 4);
  int*   srcS = (int*)alloc((size_t)EP * 4);
  float* A1   = (float*)alloc((size_t)N * 8 * 4);   // own region (gemm < fill)
  unsigned short* xs1 = (unsigned short*)alloc((size_t)N * HC1 * 2);
  unsigned short* xs2 = (unsigned short*)alloc((size_t)N * C2 * 2);
  float* A2 = (float*)alloc((size_t)N * 2 * 4);
  const size_t need = off;   // ~41 MB (ws >= 59MB per R2 evidence)

  if (ws_size < need) {  // canary: report ws MB via output
    fill_out_kernel<<<cdiv(out_size, 256), 256, 0, stream>>>(
        (float*)d_out, out_size, 131072.0f + 1024.0f * (float)(ws_size >> 20));
    return;
  }

  hipMemsetAsync(degcur, 0, ((size_t)2 * N + 256) * 4, stream);

  // K1: weight prep || edge canon + degree
  prep_edges<<<195 + cdiv(EP, 256), 256, 0, stream>>>(
      (const unsigned short*)d_in[0], d_in[1], E, EP, N,
      d_in[2], d_in[3], d_in[4], d_in[5], d_in[7], d_in[8], d_in[9], d_in[10],
      d_in[6], d_in[11],
      W1c, W2sT, W1ext, v2s, v2d, b1f, b2f, srcI, dstI, deg);

  // K2: CSR scan (blocks 0..nb) || MFMA gemm (blocks nb..nb+tiles)
  const int nb = cdiv(N, 256);
  scan_gemm<<<nb + cdiv(N, 64), 256, 0, stream>>>(
      d_in[0], (const unsigned short*)d_in[0], deg, rowst, scanflag, nb,
      W1c, W1ext, xs1, A1, N);

  // K3..K5
  fill_srcS<<<cdiv(EP, 256), 256, 0, stream>>>(srcI, dstI, EP, rowst, cursor, srcS);
  node1_merged<<<cdiv(N, 4), 256, 0, stream>>>(rowst, deg, srcS, A1, xs1,
                                               b1f, W2sT, v2s, v2d, xs2, A2, N);
  node2<<<cdiv(N, 4), 256, 0, stream>>>(rowst, deg, srcS, A2, xs2, b2f,
                                        (float*)d_out, N);
}